// Round 14
// baseline (356.885 us; speedup 1.0000x reference)
//
#include <hip/hip_runtime.h>

#define U_   2048
#define T_   200
#define H_   16
#define DU_  32
#define KP   288    // 9 K-slabs of 32: f(224, 200 real) | emb(32) | q+ct(11)+pad
#define NT   8      // tiles per wave (16 positions each)

typedef __attribute__((ext_vector_type(8))) short bf16x8;
typedef __attribute__((ext_vector_type(4))) float f32x4;

__device__ __forceinline__ unsigned short bf16_rne(float x) {
    unsigned u = __float_as_uint(x);
    return (unsigned short)((u + 0x7FFFu + ((u >> 16) & 1u)) >> 16);
}

// 8 f32 -> hi/lo bf16x8 via residual split (R11/R13-proven)
__device__ __forceinline__ void cvt8(const float* x, bf16x8& hi, bf16x8& lo) {
    union { bf16x8 v; unsigned u[4]; } H, L;
#pragma unroll
    for (int i = 0; i < 4; ++i) {
        const unsigned short h0 = bf16_rne(x[2 * i]), h1 = bf16_rne(x[2 * i + 1]);
        const float r0 = x[2 * i]     - __uint_as_float((unsigned)h0 << 16);
        const float r1 = x[2 * i + 1] - __uint_as_float((unsigned)h1 << 16);
        H.u[i] = (unsigned)h0 | ((unsigned)h1 << 16);
        L.u[i] = (unsigned)bf16_rne(r0) | ((unsigned)bf16_rne(r1) << 16);
    }
    hi = H.v; lo = L.v;
}

// ---------------------------------------------------------------------------
// Kernel 0: pack ALL of Wx into B-matrix [16][288] bf16 hi/lo.  (R13-proven)
// ---------------------------------------------------------------------------
__global__ __launch_bounds__(256) void k_wprep(
    const float* __restrict__ Wx,
    unsigned short* __restrict__ WThi, unsigned short* __restrict__ WTlo)
{
    const int idx = blockIdx.x * 256 + threadIdx.x;
    if (idx >= 16 * KP) return;
    const int n = idx / KP, k = idx - n * KP;
    const int s = k >> 5, kk = k & 31;
    float wv = 0.f;
    if (s < 7)       { if (k < 200) wv = Wx[(43 + k) * H_ + n]; }
    else if (s == 7) { wv = Wx[kk * H_ + n]; }
    else             { if (kk < 10) wv = Wx[(32 + kk) * H_ + n];
                       else if (kk == 10) wv = Wx[263 * H_ + n]; }
    const unsigned short h = bf16_rne(wv);
    WThi[idx] = h;
    WTlo[idx] = bf16_rne(wv - __uint_as_float((unsigned)h << 16));
}

// ---------------------------------------------------------------------------
// Kernel 1: fused pre via MFMA (R13 math) + SOFTWARE PIPELINE across NT=8
// tiles/wave: tile i+1's loads are issued before tile i's compute, so each
// wave keeps ~13KB in flight through its ~2000-cyc compute window. docid is
// prefetched TWO tiles ahead so the emb gather's address is resolved at
// issue (no in-order stall). 4 independent waves/block, private panes,
// NO barriers anywhere.
// ---------------------------------------------------------------------------
__global__ __launch_bounds__(256, 3) void k_pre(
    const float* __restrict__ qh, const float* __restrict__ f,
    const int* __restrict__ docid, const float* __restrict__ ct,
    const float* __restrict__ emb,
    const unsigned short* __restrict__ WThi,
    const unsigned short* __restrict__ WTlo,
    const float* __restrict__ brnn, float* __restrict__ pre)
{
    __shared__ float pane[4][16 * 204];          // 52224 B -> 3 blocks/CU
    const int t = threadIdx.x, l = t & 63, w = t >> 6;
    const int wid = blockIdx.x * 4 + w;          // 3200 waves
    const int tbase = wid * NT;
    const int r = l & 15, qd = l >> 4;

    float* pn = pane[w];
    const char* fB = (const char*)f;
    const float bias = brnn[r];

    float4 buf[13];
    float4 e0, e1;
    float qx[8];
    int did_nxt = 0;

    auto LOADF = [&](int tile) {
#pragma unroll
        for (int m = 0; m < 13; ++m)
            if (m < 12 || l < 32)
                buf[m] = *(const float4*)(fB + (size_t)tile * 12800 + (size_t)(m * 64 + l) * 16);
    };
    auto LOADQ = [&](int tile, float* dst) {
        const int pos = tile * 16 + r;
#pragma unroll
        for (int j = 0; j < 8; ++j) dst[j] = 0.f;
        if (qd == 0) {
#pragma unroll
            for (int j = 0; j < 4; ++j) {
                float2 v = *(const float2*)(qh + (size_t)pos * 10 + 2 * j);
                dst[2 * j] = v.x; dst[2 * j + 1] = v.y;
            }
        } else if (qd == 1) {
            dst[0] = qh[(size_t)pos * 10 + 8];
            dst[1] = qh[(size_t)pos * 10 + 9];
            dst[2] = ct[pos];
        }
    };

    // ---- prologue: tile 0 fully, docid for tile 1 ----
    {
        const int did0 = docid[tbase * 16 + r];
        LOADF(tbase);
        LOADQ(tbase, qx);
        e0 = *(const float4*)(emb + (size_t)did0 * 32 + qd * 8);
        e1 = *(const float4*)(emb + (size_t)did0 * 32 + qd * 8 + 4);
        if (NT > 1) did_nxt = docid[(tbase + 1) * 16 + r];
    }

#pragma unroll 1
    for (int i = 0; i < NT; ++i) {
        const int rbase = (tbase + i) * 16;

        // ---- STAGE tile i: granule g -> pane float-offset 4*(g + g/50) ----
#pragma unroll
        for (int m = 0; m < 13; ++m) {
            const int g = m * 64 + l;
            if (g < 800) *(float4*)(pn + 4 * (g + g / 50)) = buf[m];
        }

        // ---- capture tile i's emb/q operands before overwrite ----
        const float4 ce0 = e0, ce1 = e1;
        float cq[8];
#pragma unroll
        for (int j = 0; j < 8; ++j) cq[j] = qx[j];

        // ---- issue tile i+1's loads (fly under compute below) ----
        if (i + 1 < NT) {
            LOADF(tbase + i + 1);
            LOADQ(tbase + i + 1, qx);
            const int dd = did_nxt;              // resolved (issued at i-1)
            e0 = *(const float4*)(emb + (size_t)dd * 32 + qd * 8);
            e1 = *(const float4*)(emb + (size_t)dd * 32 + qd * 8 + 4);
            if (i + 2 < NT) did_nxt = docid[(tbase + i + 2) * 16 + r];
        }

        // ---- compute tile i ----
        f32x4 acc = {bias, bias, bias, bias};

#pragma unroll
        for (int s = 0; s < 7; ++s) {            // f slabs
            float xr[8];
            if (s < 6 || qd == 0) {
                const float4 a0 = *(const float4*)(pn + r * 204 + s * 32 + qd * 8);
                const float4 a1 = *(const float4*)(pn + r * 204 + s * 32 + qd * 8 + 4);
                xr[0] = a0.x; xr[1] = a0.y; xr[2] = a0.z; xr[3] = a0.w;
                xr[4] = a1.x; xr[5] = a1.y; xr[6] = a1.z; xr[7] = a1.w;
            } else {
#pragma unroll
                for (int j = 0; j < 8; ++j) xr[j] = 0.f;
            }
            bf16x8 ah, al; cvt8(xr, ah, al);
            const bf16x8 bh = *(const bf16x8*)(WThi + r * KP + s * 32 + qd * 8);
            const bf16x8 bl = *(const bf16x8*)(WTlo + r * KP + s * 32 + qd * 8);
            acc = __builtin_amdgcn_mfma_f32_16x16x32_bf16(ah, bh, acc, 0, 0, 0);
            acc = __builtin_amdgcn_mfma_f32_16x16x32_bf16(al, bh, acc, 0, 0, 0);
            acc = __builtin_amdgcn_mfma_f32_16x16x32_bf16(ah, bl, acc, 0, 0, 0);
        }
        {                                         // slab 7: emb
            float xr[8] = {ce0.x, ce0.y, ce0.z, ce0.w, ce1.x, ce1.y, ce1.z, ce1.w};
            bf16x8 ah, al; cvt8(xr, ah, al);
            const bf16x8 bh = *(const bf16x8*)(WThi + r * KP + 7 * 32 + qd * 8);
            const bf16x8 bl = *(const bf16x8*)(WTlo + r * KP + 7 * 32 + qd * 8);
            acc = __builtin_amdgcn_mfma_f32_16x16x32_bf16(ah, bh, acc, 0, 0, 0);
            acc = __builtin_amdgcn_mfma_f32_16x16x32_bf16(al, bh, acc, 0, 0, 0);
            acc = __builtin_amdgcn_mfma_f32_16x16x32_bf16(ah, bl, acc, 0, 0, 0);
        }
        {                                         // slab 8: q + ct
            bf16x8 ah, al; cvt8(cq, ah, al);
            const bf16x8 bh = *(const bf16x8*)(WThi + r * KP + 8 * 32 + qd * 8);
            const bf16x8 bl = *(const bf16x8*)(WTlo + r * KP + 8 * 32 + qd * 8);
            acc = __builtin_amdgcn_mfma_f32_16x16x32_bf16(ah, bh, acc, 0, 0, 0);
            acc = __builtin_amdgcn_mfma_f32_16x16x32_bf16(al, bh, acc, 0, 0, 0);
            acc = __builtin_amdgcn_mfma_f32_16x16x32_bf16(ah, bl, acc, 0, 0, 0);
        }

        // ---- D (m89-verified): col = l&15 = h, row = qd*4 + reg ----
#pragma unroll
        for (int ii = 0; ii < 4; ++ii)
            pre[(size_t)(rbase + qd * 4 + ii) * H_ + r] = acc[ii];
    }
}

// ---------------------------------------------------------------------------
// Kernel 2: sequential RNN scan + LeakyReLU + Dense.  (unchanged)
// ---------------------------------------------------------------------------
__device__ __forceinline__ float tanh_fast(float x) {
    float e = __expf(2.f * x);
    return 1.f - 2.f / (e + 1.f);
}

__global__ __launch_bounds__(64) void k_rnn(
    const float* __restrict__ pre, const int* __restrict__ docid,
    const float* __restrict__ Wh, const float* __restrict__ Wd,
    const float* __restrict__ bd, float* __restrict__ out)
{
    const int tid = threadIdx.x;
    const int l = tid & 15;
    const int u = (blockIdx.x * 64 + tid) >> 4;

    const float* prow = pre + (size_t)u * T_ * H_;
    const int* drow = docid + (size_t)u * T_;

    float wh[16];
#pragma unroll
    for (int k = 0; k < 16; ++k) wh[k] = Wh[((l ^ k) << 4) | l];

    float h = 0.f;

    float pb0 = prow[0 * H_ + l], pb1 = prow[1 * H_ + l],
          pb2 = prow[2 * H_ + l], pb3 = prow[3 * H_ + l];
    int   m0 = drow[0], m1 = drow[1], m2 = drow[2], m3 = drow[3];

    for (int tb = 0; tb < T_; tb += 4) {
#pragma unroll
        for (int s = 0; s < 4; ++s) {
            float p; int m;
            if      (s == 0) { p = pb0; m = m0; }
            else if (s == 1) { p = pb1; m = m1; }
            else if (s == 2) { p = pb2; m = m2; }
            else             { p = pb3; m = m3; }

            int tn = tb + 4 + s; if (tn > T_ - 1) tn = T_ - 1;
            float pn = prow[tn * H_ + l];
            int   mn = drow[tn];
            if      (s == 0) { pb0 = pn; m0 = mn; }
            else if (s == 1) { pb1 = pn; m1 = mn; }
            else if (s == 2) { pb2 = pn; m2 = mn; }
            else             { pb3 = pn; m3 = mn; }

            float a0 = p, a1 = 0.f, a2 = 0.f, a3 = 0.f;
#pragma unroll
            for (int k = 0; k < 16; k += 4) {
                a0 += __shfl_xor(h, k + 0, 16) * wh[k + 0];
                a1 += __shfl_xor(h, k + 1, 16) * wh[k + 1];
                a2 += __shfl_xor(h, k + 2, 16) * wh[k + 2];
                a3 += __shfl_xor(h, k + 3, 16) * wh[k + 3];
            }
            float accv = (a0 + a1) + (a2 + a3);
            float th = tanh_fast(accv);
            h = (m != 0) ? th : h;
        }
    }

    float a = (h >= 0.f) ? h : 0.3f * h;

    float wd0[16], wd1[16];
#pragma unroll
    for (int k = 0; k < 16; ++k) {
        int j = l ^ k;
        wd0[k] = Wd[j * DU_ + l];
        wd1[k] = Wd[j * DU_ + l + 16];
    }
    float o0 = bd[l], o1 = bd[l + 16];
#pragma unroll
    for (int k = 0; k < 16; ++k) {
        float av = __shfl_xor(a, k, 16);
        o0 += av * wd0[k];
        o1 += av * wd1[k];
    }
    out[(size_t)u * DU_ + l] = o0;
    out[(size_t)u * DU_ + l + 16] = o1;
}

// ---------------------------------------------------------------------------
extern "C" void kernel_launch(void* const* d_in, const int* in_sizes, int n_in,
                              void* d_out, int out_size, void* d_ws, size_t ws_size,
                              hipStream_t stream) {
    const float* qh    = (const float*)d_in[0];
    const float* f     = (const float*)d_in[1];
    const int*   docid = (const int*)  d_in[2];
    const float* ct    = (const float*)d_in[3];
    const float* emb   = (const float*)d_in[4];
    const float* Wx    = (const float*)d_in[5];
    const float* Wh    = (const float*)d_in[6];
    const float* brnn  = (const float*)d_in[7];
    const float* Wd    = (const float*)d_in[8];
    const float* bd    = (const float*)d_in[9];
    float* out = (float*)d_out;

    float* pre = (float*)d_ws;                                   // 26.2 MB
    unsigned short* WThi = (unsigned short*)((char*)d_ws + (size_t)U_ * T_ * H_ * 4);
    unsigned short* WTlo = WThi + 16 * KP;

    k_wprep<<<(16 * KP + 255) / 256, 256, 0, stream>>>(Wx, WThi, WTlo);
    k_pre<<<(U_ * T_) / (64 * NT), 256, 0, stream>>>(qh, f, docid, ct, emb, WThi, WTlo, brnn, pre);
    k_rnn<<<(U_ * H_) / 64, 64, 0, stream>>>(pre, docid, Wh, Wd, bd, out);
}

// Round 15
// 354.513 us; speedup vs baseline: 1.0067x; 1.0067x over previous
//
#include <hip/hip_runtime.h>

#define U_   2048
#define T_   200
#define H_   16
#define DU_  32
#define KP   288    // 9 K-slabs of 32: f(224, 200 real) | emb(32) | q+ct(11)+pad
#define NT   8      // tiles per wave (16 positions each)

typedef __attribute__((ext_vector_type(8))) short bf16x8;
typedef __attribute__((ext_vector_type(4))) float f32x4;

__device__ __forceinline__ unsigned short bf16_rne(float x) {
    unsigned u = __float_as_uint(x);
    return (unsigned short)((u + 0x7FFFu + ((u >> 16) & 1u)) >> 16);
}

// 8 f32 -> hi/lo bf16x8 via residual split (R11/R13-proven)
__device__ __forceinline__ void cvt8(const float* x, bf16x8& hi, bf16x8& lo) {
    union { bf16x8 v; unsigned u[4]; } H, L;
#pragma unroll
    for (int i = 0; i < 4; ++i) {
        const unsigned short h0 = bf16_rne(x[2 * i]), h1 = bf16_rne(x[2 * i + 1]);
        const float r0 = x[2 * i]     - __uint_as_float((unsigned)h0 << 16);
        const float r1 = x[2 * i + 1] - __uint_as_float((unsigned)h1 << 16);
        H.u[i] = (unsigned)h0 | ((unsigned)h1 << 16);
        L.u[i] = (unsigned)bf16_rne(r0) | ((unsigned)bf16_rne(r1) << 16);
    }
    hi = H.v; lo = L.v;
}

// ---------------------------------------------------------------------------
// Kernel 0: pack ALL of Wx into B-matrix [16][288] bf16 hi/lo.  (R13-proven)
// ---------------------------------------------------------------------------
__global__ __launch_bounds__(256) void k_wprep(
    const float* __restrict__ Wx,
    unsigned short* __restrict__ WThi, unsigned short* __restrict__ WTlo)
{
    const int idx = blockIdx.x * 256 + threadIdx.x;
    if (idx >= 16 * KP) return;
    const int n = idx / KP, k = idx - n * KP;
    const int s = k >> 5, kk = k & 31;
    float wv = 0.f;
    if (s < 7)       { if (k < 200) wv = Wx[(43 + k) * H_ + n]; }
    else if (s == 7) { wv = Wx[kk * H_ + n]; }
    else             { if (kk < 10) wv = Wx[(32 + kk) * H_ + n];
                       else if (kk == 10) wv = Wx[263 * H_ + n]; }
    const unsigned short h = bf16_rne(wv);
    WThi[idx] = h;
    WTlo[idx] = bf16_rne(wv - __uint_as_float((unsigned)h << 16));
}

// ---------------------------------------------------------------------------
// Kernel 1: R14 pipeline, ONE change: amdgpu_waves_per_eu(3,3) pins the
// register budget to 512/3=170 VGPR. R14's allocator chased 6 waves/EU
// (VGPR=84) and spilled the 52-reg prefetch buffer (339MB scratch) even
// though LDS caps us at 3 waves/SIMD anyway. Pinning min=max=3 makes the
// budget match the LDS-imposed occupancy -> no spill, pipeline intact.
// ---------------------------------------------------------------------------
__global__ __launch_bounds__(256)
__attribute__((amdgpu_waves_per_eu(3, 3)))
void k_pre(
    const float* __restrict__ qh, const float* __restrict__ f,
    const int* __restrict__ docid, const float* __restrict__ ct,
    const float* __restrict__ emb,
    const unsigned short* __restrict__ WThi,
    const unsigned short* __restrict__ WTlo,
    const float* __restrict__ brnn, float* __restrict__ pre)
{
    __shared__ float pane[4][16 * 204];          // 52224 B -> 3 blocks/CU
    const int t = threadIdx.x, l = t & 63, w = t >> 6;
    const int wid = blockIdx.x * 4 + w;          // 3200 waves
    const int tbase = wid * NT;
    const int r = l & 15, qd = l >> 4;

    float* pn = pane[w];
    const char* fB = (const char*)f;
    const float bias = brnn[r];

    float4 buf[13];
    float4 e0, e1;
    float qx[8];
    int did_nxt = 0;

    auto LOADF = [&](int tile) {
#pragma unroll
        for (int m = 0; m < 13; ++m)
            if (m < 12 || l < 32)
                buf[m] = *(const float4*)(fB + (size_t)tile * 12800 + (size_t)(m * 64 + l) * 16);
    };
    auto LOADQ = [&](int tile, float* dst) {
        const int pos = tile * 16 + r;
#pragma unroll
        for (int j = 0; j < 8; ++j) dst[j] = 0.f;
        if (qd == 0) {
#pragma unroll
            for (int j = 0; j < 4; ++j) {
                float2 v = *(const float2*)(qh + (size_t)pos * 10 + 2 * j);
                dst[2 * j] = v.x; dst[2 * j + 1] = v.y;
            }
        } else if (qd == 1) {
            dst[0] = qh[(size_t)pos * 10 + 8];
            dst[1] = qh[(size_t)pos * 10 + 9];
            dst[2] = ct[pos];
        }
    };

    // ---- prologue: tile 0 fully, docid for tile 1 ----
    {
        const int did0 = docid[tbase * 16 + r];
        LOADF(tbase);
        LOADQ(tbase, qx);
        e0 = *(const float4*)(emb + (size_t)did0 * 32 + qd * 8);
        e1 = *(const float4*)(emb + (size_t)did0 * 32 + qd * 8 + 4);
        if (NT > 1) did_nxt = docid[(tbase + 1) * 16 + r];
    }

#pragma unroll 1
    for (int i = 0; i < NT; ++i) {
        const int rbase = (tbase + i) * 16;

        // ---- STAGE tile i: granule g -> pane float-offset 4*(g + g/50) ----
#pragma unroll
        for (int m = 0; m < 13; ++m) {
            const int g = m * 64 + l;
            if (g < 800) *(float4*)(pn + 4 * (g + g / 50)) = buf[m];
        }

        // ---- capture tile i's emb/q operands before overwrite ----
        const float4 ce0 = e0, ce1 = e1;
        float cq[8];
#pragma unroll
        for (int j = 0; j < 8; ++j) cq[j] = qx[j];

        // ---- issue tile i+1's loads (fly under compute below) ----
        if (i + 1 < NT) {
            LOADF(tbase + i + 1);
            LOADQ(tbase + i + 1, qx);
            const int dd = did_nxt;              // resolved (issued at i-1)
            e0 = *(const float4*)(emb + (size_t)dd * 32 + qd * 8);
            e1 = *(const float4*)(emb + (size_t)dd * 32 + qd * 8 + 4);
            if (i + 2 < NT) did_nxt = docid[(tbase + i + 2) * 16 + r];
        }

        // ---- compute tile i ----
        f32x4 acc = {bias, bias, bias, bias};

#pragma unroll
        for (int s = 0; s < 7; ++s) {            // f slabs
            float xr[8];
            if (s < 6 || qd == 0) {
                const float4 a0 = *(const float4*)(pn + r * 204 + s * 32 + qd * 8);
                const float4 a1 = *(const float4*)(pn + r * 204 + s * 32 + qd * 8 + 4);
                xr[0] = a0.x; xr[1] = a0.y; xr[2] = a0.z; xr[3] = a0.w;
                xr[4] = a1.x; xr[5] = a1.y; xr[6] = a1.z; xr[7] = a1.w;
            } else {
#pragma unroll
                for (int j = 0; j < 8; ++j) xr[j] = 0.f;
            }
            bf16x8 ah, al; cvt8(xr, ah, al);
            const bf16x8 bh = *(const bf16x8*)(WThi + r * KP + s * 32 + qd * 8);
            const bf16x8 bl = *(const bf16x8*)(WTlo + r * KP + s * 32 + qd * 8);
            acc = __builtin_amdgcn_mfma_f32_16x16x32_bf16(ah, bh, acc, 0, 0, 0);
            acc = __builtin_amdgcn_mfma_f32_16x16x32_bf16(al, bh, acc, 0, 0, 0);
            acc = __builtin_amdgcn_mfma_f32_16x16x32_bf16(ah, bl, acc, 0, 0, 0);
        }
        {                                         // slab 7: emb
            float xr[8] = {ce0.x, ce0.y, ce0.z, ce0.w, ce1.x, ce1.y, ce1.z, ce1.w};
            bf16x8 ah, al; cvt8(xr, ah, al);
            const bf16x8 bh = *(const bf16x8*)(WThi + r * KP + 7 * 32 + qd * 8);
            const bf16x8 bl = *(const bf16x8*)(WTlo + r * KP + 7 * 32 + qd * 8);
            acc = __builtin_amdgcn_mfma_f32_16x16x32_bf16(ah, bh, acc, 0, 0, 0);
            acc = __builtin_amdgcn_mfma_f32_16x16x32_bf16(al, bh, acc, 0, 0, 0);
            acc = __builtin_amdgcn_mfma_f32_16x16x32_bf16(ah, bl, acc, 0, 0, 0);
        }
        {                                         // slab 8: q + ct
            bf16x8 ah, al; cvt8(cq, ah, al);
            const bf16x8 bh = *(const bf16x8*)(WThi + r * KP + 8 * 32 + qd * 8);
            const bf16x8 bl = *(const bf16x8*)(WTlo + r * KP + 8 * 32 + qd * 8);
            acc = __builtin_amdgcn_mfma_f32_16x16x32_bf16(ah, bh, acc, 0, 0, 0);
            acc = __builtin_amdgcn_mfma_f32_16x16x32_bf16(al, bh, acc, 0, 0, 0);
            acc = __builtin_amdgcn_mfma_f32_16x16x32_bf16(ah, bl, acc, 0, 0, 0);
        }

        // ---- D (m89-verified): col = l&15 = h, row = qd*4 + reg ----
#pragma unroll
        for (int ii = 0; ii < 4; ++ii)
            pre[(size_t)(rbase + qd * 4 + ii) * H_ + r] = acc[ii];
    }
}

// ---------------------------------------------------------------------------
// Kernel 2: sequential RNN scan + LeakyReLU + Dense.  (unchanged)
// ---------------------------------------------------------------------------
__device__ __forceinline__ float tanh_fast(float x) {
    float e = __expf(2.f * x);
    return 1.f - 2.f / (e + 1.f);
}

__global__ __launch_bounds__(64) void k_rnn(
    const float* __restrict__ pre, const int* __restrict__ docid,
    const float* __restrict__ Wh, const float* __restrict__ Wd,
    const float* __restrict__ bd, float* __restrict__ out)
{
    const int tid = threadIdx.x;
    const int l = tid & 15;
    const int u = (blockIdx.x * 64 + tid) >> 4;

    const float* prow = pre + (size_t)u * T_ * H_;
    const int* drow = docid + (size_t)u * T_;

    float wh[16];
#pragma unroll
    for (int k = 0; k < 16; ++k) wh[k] = Wh[((l ^ k) << 4) | l];

    float h = 0.f;

    float pb0 = prow[0 * H_ + l], pb1 = prow[1 * H_ + l],
          pb2 = prow[2 * H_ + l], pb3 = prow[3 * H_ + l];
    int   m0 = drow[0], m1 = drow[1], m2 = drow[2], m3 = drow[3];

    for (int tb = 0; tb < T_; tb += 4) {
#pragma unroll
        for (int s = 0; s < 4; ++s) {
            float p; int m;
            if      (s == 0) { p = pb0; m = m0; }
            else if (s == 1) { p = pb1; m = m1; }
            else if (s == 2) { p = pb2; m = m2; }
            else             { p = pb3; m = m3; }

            int tn = tb + 4 + s; if (tn > T_ - 1) tn = T_ - 1;
            float pn = prow[tn * H_ + l];
            int   mn = drow[tn];
            if      (s == 0) { pb0 = pn; m0 = mn; }
            else if (s == 1) { pb1 = pn; m1 = mn; }
            else if (s == 2) { pb2 = pn; m2 = mn; }
            else             { pb3 = pn; m3 = mn; }

            float a0 = p, a1 = 0.f, a2 = 0.f, a3 = 0.f;
#pragma unroll
            for (int k = 0; k < 16; k += 4) {
                a0 += __shfl_xor(h, k + 0, 16) * wh[k + 0];
                a1 += __shfl_xor(h, k + 1, 16) * wh[k + 1];
                a2 += __shfl_xor(h, k + 2, 16) * wh[k + 2];
                a3 += __shfl_xor(h, k + 3, 16) * wh[k + 3];
            }
            float accv = (a0 + a1) + (a2 + a3);
            float th = tanh_fast(accv);
            h = (m != 0) ? th : h;
        }
    }

    float a = (h >= 0.f) ? h : 0.3f * h;

    float wd0[16], wd1[16];
#pragma unroll
    for (int k = 0; k < 16; ++k) {
        int j = l ^ k;
        wd0[k] = Wd[j * DU_ + l];
        wd1[k] = Wd[j * DU_ + l + 16];
    }
    float o0 = bd[l], o1 = bd[l + 16];
#pragma unroll
    for (int k = 0; k < 16; ++k) {
        float av = __shfl_xor(a, k, 16);
        o0 += av * wd0[k];
        o1 += av * wd1[k];
    }
    out[(size_t)u * DU_ + l] = o0;
    out[(size_t)u * DU_ + l + 16] = o1;
}

// ---------------------------------------------------------------------------
extern "C" void kernel_launch(void* const* d_in, const int* in_sizes, int n_in,
                              void* d_out, int out_size, void* d_ws, size_t ws_size,
                              hipStream_t stream) {
    const float* qh    = (const float*)d_in[0];
    const float* f     = (const float*)d_in[1];
    const int*   docid = (const int*)  d_in[2];
    const float* ct    = (const float*)d_in[3];
    const float* emb   = (const float*)d_in[4];
    const float* Wx    = (const float*)d_in[5];
    const float* Wh    = (const float*)d_in[6];
    const float* brnn  = (const float*)d_in[7];
    const float* Wd    = (const float*)d_in[8];
    const float* bd    = (const float*)d_in[9];
    float* out = (float*)d_out;

    float* pre = (float*)d_ws;                                   // 26.2 MB
    unsigned short* WThi = (unsigned short*)((char*)d_ws + (size_t)U_ * T_ * H_ * 4);
    unsigned short* WTlo = WThi + 16 * KP;

    k_wprep<<<(16 * KP + 255) / 256, 256, 0, stream>>>(Wx, WThi, WTlo);
    k_pre<<<(U_ * T_) / (64 * NT), 256, 0, stream>>>(qh, f, docid, ct, emb, WThi, WTlo, brnn, pre);
    k_rnn<<<(U_ * H_) / 64, 64, 0, stream>>>(pre, docid, Wh, Wd, bd, out);
}

// Round 16
// 182.021 us; speedup vs baseline: 1.9607x; 1.9476x over previous
//
#include <hip/hip_runtime.h>

#define U_   2048
#define T_   200
#define H_   16
#define DU_  32
#define KP   288    // 9 K-slabs of 32: f(224, 200 real) | emb(32) | q+ct(11)+pad
#define NT   8      // tiles per wave (16 positions each)

typedef __attribute__((ext_vector_type(8))) short bf16x8;
typedef __attribute__((ext_vector_type(4))) float f32x4;

__device__ __forceinline__ unsigned short bf16_rne(float x) {
    unsigned u = __float_as_uint(x);
    return (unsigned short)((u + 0x7FFFu + ((u >> 16) & 1u)) >> 16);
}

// 8 f32 -> hi/lo bf16x8 via residual split (R11/R13-proven)
__device__ __forceinline__ void cvt8(const float* x, bf16x8& hi, bf16x8& lo) {
    union { bf16x8 v; unsigned u[4]; } H, L;
#pragma unroll
    for (int i = 0; i < 4; ++i) {
        const unsigned short h0 = bf16_rne(x[2 * i]), h1 = bf16_rne(x[2 * i + 1]);
        const float r0 = x[2 * i]     - __uint_as_float((unsigned)h0 << 16);
        const float r1 = x[2 * i + 1] - __uint_as_float((unsigned)h1 << 16);
        H.u[i] = (unsigned)h0 | ((unsigned)h1 << 16);
        L.u[i] = (unsigned)bf16_rne(r0) | ((unsigned)bf16_rne(r1) << 16);
    }
    hi = H.v; lo = L.v;
}

__device__ __forceinline__ void g2l16(const void* g, void* l) {
    __builtin_amdgcn_global_load_lds(
        (const __attribute__((address_space(1))) void*)g,
        (__attribute__((address_space(3))) void*)l, 16, 0, 0);
}

// ---------------------------------------------------------------------------
// Kernel 0: pack ALL of Wx into B-matrix [16][288] bf16 hi/lo.  (R13-proven)
// ---------------------------------------------------------------------------
__global__ __launch_bounds__(256) void k_wprep(
    const float* __restrict__ Wx,
    unsigned short* __restrict__ WThi, unsigned short* __restrict__ WTlo)
{
    const int idx = blockIdx.x * 256 + threadIdx.x;
    if (idx >= 16 * KP) return;
    const int n = idx / KP, k = idx - n * KP;
    const int s = k >> 5, kk = k & 31;
    float wv = 0.f;
    if (s < 7)       { if (k < 200) wv = Wx[(43 + k) * H_ + n]; }
    else if (s == 7) { wv = Wx[kk * H_ + n]; }
    else             { if (kk < 10) wv = Wx[(32 + kk) * H_ + n];
                       else if (kk == 10) wv = Wx[263 * H_ + n]; }
    const unsigned short h = bf16_rne(wv);
    WThi[idx] = h;
    WTlo[idx] = bf16_rne(wv - __uint_as_float((unsigned)h << 16));
}

// ---------------------------------------------------------------------------
// Kernel 1: fused pre via MFMA (R13 math) + PER-WAVE g2l16 double-buffer.
// Block = 1 wave, 2 private LDS panes, NO barriers, NO data registers for
// staging (DMA). vmcnt(0) at iter top = the only throttle. Source-side XOR
// swizzle (slot holds granule g2^(p&7)) with same-XOR reads -> b128 bank
// floor (rule #21; dst must stay linear per m104).
// ---------------------------------------------------------------------------
__global__ __launch_bounds__(64) void k_pre(
    const float* __restrict__ qh, const float* __restrict__ f,
    const int* __restrict__ docid, const float* __restrict__ ct,
    const float* __restrict__ emb,
    const unsigned short* __restrict__ WThi,
    const unsigned short* __restrict__ WTlo,
    const float* __restrict__ brnn, float* __restrict__ pre)
{
    __shared__ float pane[2][13 * 64 * 4];       // 2 x 13312B (64 pad slots incl.)
    const int l = threadIdx.x;
    const int r = l & 15, qd = l >> 4;
    const int tbase = blockIdx.x * NT;           // grid 3200 exact
    const char* fB = (const char*)f;

    // per-lane swizzled source offsets within a tile (slot m*64+l)
    int off[13];
#pragma unroll
    for (int m = 0; m < 13; ++m) {
        const int slot = m * 64 + l;
        if (slot < 800) {
            const int p = slot / 50, g2 = slot - 50 * p;
            const int gr = (g2 < 48) ? (g2 ^ (p & 7)) : g2;
            off[m] = p * 800 + gr * 16;
        } else off[m] = 0;                        // pad slot: reads tile base
    }

    auto STAGE = [&](int tile, int b) {
        const char* src = fB + (size_t)tile * 12800;
        char* dst = (char*)pane[b];
#pragma unroll
        for (int m = 0; m < 13; ++m)
            g2l16(src + off[m], dst + m * 1024); // uniform dst; HW adds lane*16
    };

    const float bias = brnn[r];
    int did = docid[tbase * 16 + r];

    STAGE(tbase, 0);                              // prologue: tile 0 -> pane0

#pragma unroll 1
    for (int i = 0; i < NT; ++i) {
        const int cur = i & 1;
        asm volatile("s_waitcnt vmcnt(0)" ::: "memory");   // pane[cur] resident
        __builtin_amdgcn_sched_barrier(0);

        if (i + 1 < NT) STAGE(tbase + i + 1, cur ^ 1);     // next tile in flight

        // ---- tile i operand loads (consumed at slabs 7-8, ~1400cy later) ----
        const int pos = (tbase + i) * 16 + r;
        const float4 e0 = *(const float4*)(emb + (size_t)did * 32 + qd * 8);
        const float4 e1 = *(const float4*)(emb + (size_t)did * 32 + qd * 8 + 4);
        int did_n = did;
        if (i + 1 < NT) did_n = docid[(tbase + i + 1) * 16 + r];
        float qx[8];
#pragma unroll
        for (int j = 0; j < 8; ++j) qx[j] = 0.f;
        if (qd == 0) {
#pragma unroll
            for (int j = 0; j < 4; ++j) {
                float2 v = *(const float2*)(qh + (size_t)pos * 10 + 2 * j);
                qx[2 * j] = v.x; qx[2 * j + 1] = v.y;
            }
        } else if (qd == 1) {
            qx[0] = qh[(size_t)pos * 10 + 8];
            qx[1] = qh[(size_t)pos * 10 + 9];
            qx[2] = ct[pos];
        }

        // ---- compute tile i from pane[cur] ----
        const float4* pc = (const float4*)pane[cur];
        f32x4 acc = {bias, bias, bias, bias};

#pragma unroll
        for (int s = 0; s < 7; ++s) {
            float xr[8];
            if (s < 6) {
                const int a0 = 50 * r + ((8 * s + 2 * qd) ^ (r & 7));
                const float4 v0 = pc[a0];
                const float4 v1 = pc[a0 ^ 1];    // (+1 granule, same XOR class)
                xr[0] = v0.x; xr[1] = v0.y; xr[2] = v0.z; xr[3] = v0.w;
                xr[4] = v1.x; xr[5] = v1.y; xr[6] = v1.z; xr[7] = v1.w;
            } else if (qd == 0) {                // gr 48,49 unswizzled
                const float4 v0 = pc[50 * r + 48];
                const float4 v1 = pc[50 * r + 49];
                xr[0] = v0.x; xr[1] = v0.y; xr[2] = v0.z; xr[3] = v0.w;
                xr[4] = v1.x; xr[5] = v1.y; xr[6] = v1.z; xr[7] = v1.w;
            } else {
#pragma unroll
                for (int j = 0; j < 8; ++j) xr[j] = 0.f;   // zero-weight cols
            }
            bf16x8 ah, al; cvt8(xr, ah, al);
            const bf16x8 bh = *(const bf16x8*)(WThi + r * KP + s * 32 + qd * 8);
            const bf16x8 bl = *(const bf16x8*)(WTlo + r * KP + s * 32 + qd * 8);
            acc = __builtin_amdgcn_mfma_f32_16x16x32_bf16(ah, bh, acc, 0, 0, 0);
            acc = __builtin_amdgcn_mfma_f32_16x16x32_bf16(al, bh, acc, 0, 0, 0);
            acc = __builtin_amdgcn_mfma_f32_16x16x32_bf16(ah, bl, acc, 0, 0, 0);
        }
        {                                         // slab 7: emb
            float xr[8] = {e0.x, e0.y, e0.z, e0.w, e1.x, e1.y, e1.z, e1.w};
            bf16x8 ah, al; cvt8(xr, ah, al);
            const bf16x8 bh = *(const bf16x8*)(WThi + r * KP + 7 * 32 + qd * 8);
            const bf16x8 bl = *(const bf16x8*)(WTlo + r * KP + 7 * 32 + qd * 8);
            acc = __builtin_amdgcn_mfma_f32_16x16x32_bf16(ah, bh, acc, 0, 0, 0);
            acc = __builtin_amdgcn_mfma_f32_16x16x32_bf16(al, bh, acc, 0, 0, 0);
            acc = __builtin_amdgcn_mfma_f32_16x16x32_bf16(ah, bl, acc, 0, 0, 0);
        }
        {                                         // slab 8: q + ct
            bf16x8 ah, al; cvt8(qx, ah, al);
            const bf16x8 bh = *(const bf16x8*)(WThi + r * KP + 8 * 32 + qd * 8);
            const bf16x8 bl = *(const bf16x8*)(WTlo + r * KP + 8 * 32 + qd * 8);
            acc = __builtin_amdgcn_mfma_f32_16x16x32_bf16(ah, bh, acc, 0, 0, 0);
            acc = __builtin_amdgcn_mfma_f32_16x16x32_bf16(al, bh, acc, 0, 0, 0);
            acc = __builtin_amdgcn_mfma_f32_16x16x32_bf16(ah, bl, acc, 0, 0, 0);
        }

        // ---- D (m89-verified): col = l&15 = h, row = qd*4 + reg ----
        const int rbase = (tbase + i) * 16;
#pragma unroll
        for (int ii = 0; ii < 4; ++ii)
            pre[(size_t)(rbase + qd * 4 + ii) * H_ + r] = acc[ii];

        did = did_n;
    }
}

// ---------------------------------------------------------------------------
// Kernel 2: sequential RNN scan + LeakyReLU + Dense.  (unchanged)
// ---------------------------------------------------------------------------
__device__ __forceinline__ float tanh_fast(float x) {
    float e = __expf(2.f * x);
    return 1.f - 2.f / (e + 1.f);
}

__global__ __launch_bounds__(64) void k_rnn(
    const float* __restrict__ pre, const int* __restrict__ docid,
    const float* __restrict__ Wh, const float* __restrict__ Wd,
    const float* __restrict__ bd, float* __restrict__ out)
{
    const int tid = threadIdx.x;
    const int l = tid & 15;
    const int u = (blockIdx.x * 64 + tid) >> 4;

    const float* prow = pre + (size_t)u * T_ * H_;
    const int* drow = docid + (size_t)u * T_;

    float wh[16];
#pragma unroll
    for (int k = 0; k < 16; ++k) wh[k] = Wh[((l ^ k) << 4) | l];

    float h = 0.f;

    float pb0 = prow[0 * H_ + l], pb1 = prow[1 * H_ + l],
          pb2 = prow[2 * H_ + l], pb3 = prow[3 * H_ + l];
    int   m0 = drow[0], m1 = drow[1], m2 = drow[2], m3 = drow[3];

    for (int tb = 0; tb < T_; tb += 4) {
#pragma unroll
        for (int s = 0; s < 4; ++s) {
            float p; int m;
            if      (s == 0) { p = pb0; m = m0; }
            else if (s == 1) { p = pb1; m = m1; }
            else if (s == 2) { p = pb2; m = m2; }
            else             { p = pb3; m = m3; }

            int tn = tb + 4 + s; if (tn > T_ - 1) tn = T_ - 1;
            float pn = prow[tn * H_ + l];
            int   mn = drow[tn];
            if      (s == 0) { pb0 = pn; m0 = mn; }
            else if (s == 1) { pb1 = pn; m1 = mn; }
            else if (s == 2) { pb2 = pn; m2 = mn; }
            else             { pb3 = pn; m3 = mn; }

            float a0 = p, a1 = 0.f, a2 = 0.f, a3 = 0.f;
#pragma unroll
            for (int k = 0; k < 16; k += 4) {
                a0 += __shfl_xor(h, k + 0, 16) * wh[k + 0];
                a1 += __shfl_xor(h, k + 1, 16) * wh[k + 1];
                a2 += __shfl_xor(h, k + 2, 16) * wh[k + 2];
                a3 += __shfl_xor(h, k + 3, 16) * wh[k + 3];
            }
            float accv = (a0 + a1) + (a2 + a3);
            float th = tanh_fast(accv);
            h = (m != 0) ? th : h;
        }
    }

    float a = (h >= 0.f) ? h : 0.3f * h;

    float wd0[16], wd1[16];
#pragma unroll
    for (int k = 0; k < 16; ++k) {
        int j = l ^ k;
        wd0[k] = Wd[j * DU_ + l];
        wd1[k] = Wd[j * DU_ + l + 16];
    }
    float o0 = bd[l], o1 = bd[l + 16];
#pragma unroll
    for (int k = 0; k < 16; ++k) {
        float av = __shfl_xor(a, k, 16);
        o0 += av * wd0[k];
        o1 += av * wd1[k];
    }
    out[(size_t)u * DU_ + l] = o0;
    out[(size_t)u * DU_ + l + 16] = o1;
}

// ---------------------------------------------------------------------------
extern "C" void kernel_launch(void* const* d_in, const int* in_sizes, int n_in,
                              void* d_out, int out_size, void* d_ws, size_t ws_size,
                              hipStream_t stream) {
    const float* qh    = (const float*)d_in[0];
    const float* f     = (const float*)d_in[1];
    const int*   docid = (const int*)  d_in[2];
    const float* ct    = (const float*)d_in[3];
    const float* emb   = (const float*)d_in[4];
    const float* Wx    = (const float*)d_in[5];
    const float* Wh    = (const float*)d_in[6];
    const float* brnn  = (const float*)d_in[7];
    const float* Wd    = (const float*)d_in[8];
    const float* bd    = (const float*)d_in[9];
    float* out = (float*)d_out;

    float* pre = (float*)d_ws;                                   // 26.2 MB
    unsigned short* WThi = (unsigned short*)((char*)d_ws + (size_t)U_ * T_ * H_ * 4);
    unsigned short* WTlo = WThi + 16 * KP;

    k_wprep<<<(16 * KP + 255) / 256, 256, 0, stream>>>(Wx, WThi, WTlo);
    k_pre<<<(U_ * T_) / (16 * NT), 64, 0, stream>>>(qh, f, docid, ct, emb, WThi, WTlo, brnn, pre);
    k_rnn<<<(U_ * H_) / 64, 64, 0, stream>>>(pre, docid, Wh, Wd, bd, out);
}

// Round 17
// 153.876 us; speedup vs baseline: 2.3193x; 1.1829x over previous
//
#include <hip/hip_runtime.h>

#define U_   2048
#define T_   200
#define H_   16
#define DU_  32
#define KP   288    // 9 K-slabs of 32: f(224, 200 real) | emb(32) | q+ct(11)+pad

typedef __attribute__((ext_vector_type(8))) short bf16x8;
typedef __attribute__((ext_vector_type(4))) float f32x4;

__device__ __forceinline__ unsigned short bf16_rne(float x) {
    unsigned u = __float_as_uint(x);
    return (unsigned short)((u + 0x7FFFu + ((u >> 16) & 1u)) >> 16);
}

// 8 f32 -> hi/lo bf16x8 via residual split (R11/R13-proven)
__device__ __forceinline__ void cvt8(const float* x, bf16x8& hi, bf16x8& lo) {
    union { bf16x8 v; unsigned u[4]; } H, L;
#pragma unroll
    for (int i = 0; i < 4; ++i) {
        const unsigned short h0 = bf16_rne(x[2 * i]), h1 = bf16_rne(x[2 * i + 1]);
        const float r0 = x[2 * i]     - __uint_as_float((unsigned)h0 << 16);
        const float r1 = x[2 * i + 1] - __uint_as_float((unsigned)h1 << 16);
        H.u[i] = (unsigned)h0 | ((unsigned)h1 << 16);
        L.u[i] = (unsigned)bf16_rne(r0) | ((unsigned)bf16_rne(r1) << 16);
    }
    hi = H.v; lo = L.v;
}

// ---------------------------------------------------------------------------
// Kernel 0: pack ALL of Wx (f rows 43..242 | emb rows 0..31 | q rows 32..41 +
// ct row 263) into B-matrix [n=16][KP=288] bf16 hi/lo, zeros in pad cols.
// ---------------------------------------------------------------------------
__global__ __launch_bounds__(256) void k_wprep(
    const float* __restrict__ Wx,
    unsigned short* __restrict__ WThi, unsigned short* __restrict__ WTlo)
{
    const int idx = blockIdx.x * 256 + threadIdx.x;
    if (idx >= 16 * KP) return;
    const int n = idx / KP, k = idx - n * KP;
    const int s = k >> 5, kk = k & 31;
    float wv = 0.f;
    if (s < 7)       { if (k < 200) wv = Wx[(43 + k) * H_ + n]; }
    else if (s == 7) { wv = Wx[kk * H_ + n]; }
    else             { if (kk < 10) wv = Wx[(32 + kk) * H_ + n];
                       else if (kk == 10) wv = Wx[263 * H_ + n]; }
    const unsigned short h = bf16_rne(wv);
    WThi[idx] = h;
    WTlo[idx] = bf16_rne(wv - __uint_as_float((unsigned)h << 16));
}

// ---------------------------------------------------------------------------
// Kernel 1: pre[pos,h] = brnn[h] + x[pos,:].Wx[:,h]  — fully fused via MFMA.
// (R13, the session best: 152.4 us total, absmax 0.0078.)
// Wave = 16 consecutive positions = ONE CONTIGUOUS 12800B f-block = 800
// granules = 13 load rounds/lane. Reg->LDS f32 pane (rows padded to 204
// floats), cvt-to-bf16 at fragment read; 9 K-slabs x 3 MFMA (hi/lo residual).
// 4 independent waves/block, private panes, NO barriers. k_pre runs at
// ~2.9 TB/s combined = the empirical HBM read-round-trip ceiling of this box
// (copy ubench reads ~3.1; every other structure tried lands 1.4-2.4).
// ---------------------------------------------------------------------------
__global__ __launch_bounds__(256, 3) void k_pre(
    const float* __restrict__ qh, const float* __restrict__ f,
    const int* __restrict__ docid, const float* __restrict__ ct,
    const float* __restrict__ emb,
    const unsigned short* __restrict__ WThi,
    const unsigned short* __restrict__ WTlo,
    const float* __restrict__ brnn, float* __restrict__ pre)
{
    __shared__ float pane[4][16 * 204];          // 52224 B -> 3 blocks/CU
    const int t = threadIdx.x, l = t & 63, w = t >> 6;
    const int tile = blockIdx.x * 4 + w;         // 25600 tiles
    const int rbase = tile * 16;
    const int r = l & 15, qd = l >> 4;
    const int pos = rbase + r;

    // ---- 13 contiguous 1KB wave-loads: granules 0..799 of the tile ----
    const char* fsrc = (const char*)f + (size_t)rbase * 800;
    float4 buf[13];
#pragma unroll
    for (int m = 0; m < 13; ++m)
        if (m < 12 || l < 32)                     // round 12: g=768+l < 800
            buf[m] = *(const float4*)(fsrc + (size_t)(m * 64 + l) * 16);

    // ---- direct loads (latency hides under staging/compute) ----
    const int did = docid[pos];
    const float4 e0 = *(const float4*)(emb + (size_t)did * 32 + qd * 8);
    const float4 e1 = *(const float4*)(emb + (size_t)did * 32 + qd * 8 + 4);

    float qx[8];
#pragma unroll
    for (int i = 0; i < 8; ++i) qx[i] = 0.f;
    if (qd == 0) {
#pragma unroll
        for (int j = 0; j < 4; ++j) {
            float2 v = *(const float2*)(qh + (size_t)pos * 10 + 2 * j);
            qx[2 * j] = v.x; qx[2 * j + 1] = v.y;
        }
    } else if (qd == 1) {
        qx[0] = qh[(size_t)pos * 10 + 8];
        qx[1] = qh[(size_t)pos * 10 + 9];
        qx[2] = ct[pos];
    }
    const float bias = brnn[r];

    // ---- stage: granule g -> pane float-offset 4*(g + g/50) = 204*pos+4*col ----
    float* pn = pane[w];
#pragma unroll
    for (int m = 0; m < 13; ++m) {
        const int g = m * 64 + l;
        if (g < 800) *(float4*)(pn + 4 * (g + g / 50)) = buf[m];
    }

    f32x4 acc = {bias, bias, bias, bias};

    // ---- f slabs 0..6 (slab 6: only qd==0 holds real cols 192..199) ----
#pragma unroll
    for (int s = 0; s < 7; ++s) {
        float xr[8];
        if (s < 6 || qd == 0) {
            const float4 a0 = *(const float4*)(pn + r * 204 + s * 32 + qd * 8);
            const float4 a1 = *(const float4*)(pn + r * 204 + s * 32 + qd * 8 + 4);
            xr[0] = a0.x; xr[1] = a0.y; xr[2] = a0.z; xr[3] = a0.w;
            xr[4] = a1.x; xr[5] = a1.y; xr[6] = a1.z; xr[7] = a1.w;
        } else {
#pragma unroll
            for (int i = 0; i < 8; ++i) xr[i] = 0.f;
        }
        bf16x8 ah, al; cvt8(xr, ah, al);
        const bf16x8 bh = *(const bf16x8*)(WThi + r * KP + s * 32 + qd * 8);
        const bf16x8 bl = *(const bf16x8*)(WTlo + r * KP + s * 32 + qd * 8);
        acc = __builtin_amdgcn_mfma_f32_16x16x32_bf16(ah, bh, acc, 0, 0, 0);
        acc = __builtin_amdgcn_mfma_f32_16x16x32_bf16(al, bh, acc, 0, 0, 0);
        acc = __builtin_amdgcn_mfma_f32_16x16x32_bf16(ah, bl, acc, 0, 0, 0);
    }

    // ---- slab 7: emb ----
    {
        float xr[8] = {e0.x, e0.y, e0.z, e0.w, e1.x, e1.y, e1.z, e1.w};
        bf16x8 ah, al; cvt8(xr, ah, al);
        const bf16x8 bh = *(const bf16x8*)(WThi + r * KP + 7 * 32 + qd * 8);
        const bf16x8 bl = *(const bf16x8*)(WTlo + r * KP + 7 * 32 + qd * 8);
        acc = __builtin_amdgcn_mfma_f32_16x16x32_bf16(ah, bh, acc, 0, 0, 0);
        acc = __builtin_amdgcn_mfma_f32_16x16x32_bf16(al, bh, acc, 0, 0, 0);
        acc = __builtin_amdgcn_mfma_f32_16x16x32_bf16(ah, bl, acc, 0, 0, 0);
    }
    // ---- slab 8: q + ct ----
    {
        bf16x8 ah, al; cvt8(qx, ah, al);
        const bf16x8 bh = *(const bf16x8*)(WThi + r * KP + 8 * 32 + qd * 8);
        const bf16x8 bl = *(const bf16x8*)(WTlo + r * KP + 8 * 32 + qd * 8);
        acc = __builtin_amdgcn_mfma_f32_16x16x32_bf16(ah, bh, acc, 0, 0, 0);
        acc = __builtin_amdgcn_mfma_f32_16x16x32_bf16(al, bh, acc, 0, 0, 0);
        acc = __builtin_amdgcn_mfma_f32_16x16x32_bf16(ah, bl, acc, 0, 0, 0);
    }

    // ---- D (m89/R11-verified): col = l&15 = h, row = qd*4 + reg ----
#pragma unroll
    for (int i = 0; i < 4; ++i)
        pre[(size_t)(rbase + qd * 4 + i) * H_ + r] = acc[i];
}

// ---------------------------------------------------------------------------
// Kernel 2: sequential RNN scan + LeakyReLU + Dense.  (unchanged all session;
// 27.6MB at ~2.1 TB/s ~= 13 us, near the same read ceiling.)
// ---------------------------------------------------------------------------
__device__ __forceinline__ float tanh_fast(float x) {
    float e = __expf(2.f * x);
    return 1.f - 2.f / (e + 1.f);
}

__global__ __launch_bounds__(64) void k_rnn(
    const float* __restrict__ pre, const int* __restrict__ docid,
    const float* __restrict__ Wh, const float* __restrict__ Wd,
    const float* __restrict__ bd, float* __restrict__ out)
{
    const int tid = threadIdx.x;
    const int l = tid & 15;
    const int u = (blockIdx.x * 64 + tid) >> 4;

    const float* prow = pre + (size_t)u * T_ * H_;
    const int* drow = docid + (size_t)u * T_;

    float wh[16];
#pragma unroll
    for (int k = 0; k < 16; ++k) wh[k] = Wh[((l ^ k) << 4) | l];

    float h = 0.f;

    float pb0 = prow[0 * H_ + l], pb1 = prow[1 * H_ + l],
          pb2 = prow[2 * H_ + l], pb3 = prow[3 * H_ + l];
    int   m0 = drow[0], m1 = drow[1], m2 = drow[2], m3 = drow[3];

    for (int tb = 0; tb < T_; tb += 4) {
#pragma unroll
        for (int s = 0; s < 4; ++s) {
            float p; int m;
            if      (s == 0) { p = pb0; m = m0; }
            else if (s == 1) { p = pb1; m = m1; }
            else if (s == 2) { p = pb2; m = m2; }
            else             { p = pb3; m = m3; }

            int tn = tb + 4 + s; if (tn > T_ - 1) tn = T_ - 1;
            float pn = prow[tn * H_ + l];
            int   mn = drow[tn];
            if      (s == 0) { pb0 = pn; m0 = mn; }
            else if (s == 1) { pb1 = pn; m1 = mn; }
            else if (s == 2) { pb2 = pn; m2 = mn; }
            else             { pb3 = pn; m3 = mn; }

            float a0 = p, a1 = 0.f, a2 = 0.f, a3 = 0.f;
#pragma unroll
            for (int k = 0; k < 16; k += 4) {
                a0 += __shfl_xor(h, k + 0, 16) * wh[k + 0];
                a1 += __shfl_xor(h, k + 1, 16) * wh[k + 1];
                a2 += __shfl_xor(h, k + 2, 16) * wh[k + 2];
                a3 += __shfl_xor(h, k + 3, 16) * wh[k + 3];
            }
            float accv = (a0 + a1) + (a2 + a3);
            float th = tanh_fast(accv);
            h = (m != 0) ? th : h;
        }
    }

    float a = (h >= 0.f) ? h : 0.3f * h;

    float wd0[16], wd1[16];
#pragma unroll
    for (int k = 0; k < 16; ++k) {
        int j = l ^ k;
        wd0[k] = Wd[j * DU_ + l];
        wd1[k] = Wd[j * DU_ + l + 16];
    }
    float o0 = bd[l], o1 = bd[l + 16];
#pragma unroll
    for (int k = 0; k < 16; ++k) {
        float av = __shfl_xor(a, k, 16);
        o0 += av * wd0[k];
        o1 += av * wd1[k];
    }
    out[(size_t)u * DU_ + l] = o0;
    out[(size_t)u * DU_ + l + 16] = o1;
}

// ---------------------------------------------------------------------------
extern "C" void kernel_launch(void* const* d_in, const int* in_sizes, int n_in,
                              void* d_out, int out_size, void* d_ws, size_t ws_size,
                              hipStream_t stream) {
    const float* qh    = (const float*)d_in[0];
    const float* f     = (const float*)d_in[1];
    const int*   docid = (const int*)  d_in[2];
    const float* ct    = (const float*)d_in[3];
    const float* emb   = (const float*)d_in[4];
    const float* Wx    = (const float*)d_in[5];
    const float* Wh    = (const float*)d_in[6];
    const float* brnn  = (const float*)d_in[7];
    const float* Wd    = (const float*)d_in[8];
    const float* bd    = (const float*)d_in[9];
    float* out = (float*)d_out;

    float* pre = (float*)d_ws;                                   // 26.2 MB
    unsigned short* WThi = (unsigned short*)((char*)d_ws + (size_t)U_ * T_ * H_ * 4);
    unsigned short* WTlo = WThi + 16 * KP;

    k_wprep<<<(16 * KP + 255) / 256, 256, 0, stream>>>(Wx, WThi, WTlo);
    k_pre<<<(U_ * T_) / 64, 256, 0, stream>>>(qh, f, docid, ct, emb, WThi, WTlo, brnn, pre);
    k_rnn<<<(U_ * H_) / 64, 64, 0, stream>>>(pre, docid, Wh, Wd, bd, out);
}